// Round 16
// baseline (289.424 us; speedup 1.0000x reference)
//
#include <hip/hip_runtime.h>
#include <math.h>

// Problem constants (fixed by reference)
#define NR 2048
#define MC 131072
#define DIM 64
#define KSEL 11                    // k+1 smallest kept per row
#define PPART 64                   // column partitions
#define PART_COLS (MC / PPART)     // 2048 cols per partition
#define CHUNK 128                  // cols per LDS chunk
#define NCHUNK (PART_COLS / CHUNK) // 16
#define ROWS_PER_BLOCK 64          // 4 waves x 16 rows
#define QSLOT 13                   // f32 queue slots per lane, SLOT-MAJOR:
                                   // qmem[w][slot*64 + lane] -> bank = lane%32,
                                   // uniform 2 lanes/bank for ANY qo divergence
#define QCAP 12                    // insurance keeps qo <= 8 pre-push; group
                                   // push writes slots qo..qo+3 <= 11 < 13

typedef _Float16 v8h __attribute__((ext_vector_type(8)));
typedef float v4f __attribute__((ext_vector_type(4)));

// ---------------- prep: HALF-norm 0.5*|b|^2 (fp32) + buf -> f16 ----------------
// u-space: k_main computes u = 0.5*bn - dot = 0.5*(d2 - xn) directly in the
// MFMA accumulator (C init = 0.5*bn, x fragments negated).
__global__ __launch_bounds__(256) void k_prep_b(const float* __restrict__ buf,
                                                _Float16* __restrict__ B16,
                                                float* __restrict__ bnorm) {
  int gid = blockIdx.x * 256 + threadIdx.x;   // 4 threads per buffer row
  int row = gid >> 2, q = gid & 3;
  const float4* src = (const float4*)(buf + (size_t)row * DIM + q * 16);
  float4 f0 = src[0], f1 = src[1], f2 = src[2], f3 = src[3];
  float s = f0.x*f0.x + f0.y*f0.y + f0.z*f0.z + f0.w*f0.w
          + f1.x*f1.x + f1.y*f1.y + f1.z*f1.z + f1.w*f1.w
          + f2.x*f2.x + f2.y*f2.y + f2.z*f2.z + f2.w*f2.w
          + f3.x*f3.x + f3.y*f3.y + f3.z*f3.z + f3.w*f3.w;
  s += __shfl_xor(s, 1);
  s += __shfl_xor(s, 2);
  if (q == 0) bnorm[row] = s * 0.5f;          // HALF norm (u-space C operand)
  union { _Float16 h[16]; uint4 u[2]; } o;
  o.h[0]=(_Float16)f0.x; o.h[1]=(_Float16)f0.y; o.h[2]=(_Float16)f0.z; o.h[3]=(_Float16)f0.w;
  o.h[4]=(_Float16)f1.x; o.h[5]=(_Float16)f1.y; o.h[6]=(_Float16)f1.z; o.h[7]=(_Float16)f1.w;
  o.h[8]=(_Float16)f2.x; o.h[9]=(_Float16)f2.y; o.h[10]=(_Float16)f2.z; o.h[11]=(_Float16)f2.w;
  o.h[12]=(_Float16)f3.x; o.h[13]=(_Float16)f3.y; o.h[14]=(_Float16)f3.z; o.h[15]=(_Float16)f3.w;
  uint4* dst = (uint4*)(B16 + (size_t)row * DIM + q * 16);
  dst[0] = o.u[0]; dst[1] = o.u[1];
}

// branchless bubble-insert into sorted-ascending 11-list. Inserting any value
// >= lst[10] (incl. +inf) is a no-op (it bubbles off the end). 22 min/max ops.
__device__ __forceinline__ void bins11(float v, float lst[KSEL]) {
  float t = v;
#pragma unroll
  for (int j = 0; j < KSEL; ++j) {
    float a = fminf(lst[j], t);
    t = fmaxf(lst[j], t);
    lst[j] = a;
  }
}

// ---------------- main: MFMA in u-space + f32 queue + sorted top-11 ----------
// R15 structure (213us best: swizzled 16B-block tile, 2x ds_read_b128/mt
// frags, named-register staging, slot-major queue, odd-c drain cadence,
// 5 blocks/CU) with ONE change: GROUP-OF-4 PUSH. R15's issue-budget math
// puts the per-candidate push (4 cmp + 4 cursor-add + 4 write = 12 ops/mt)
// at ~70% of scan VALU. Group push: m = min(t0..t3) (min3+min), ALWAYS write
// the 4 slots, advance qo by 4 only if m < thrx (~8 ops/mt, -25% chunk
// VALU). Semantics identical: a group is dropped only when m >= thrx ==>
// every t >= thrx, the same per-candidate drop condition as before; junk
// never enters (slots become live only when the group passes). qo is now
// always a multiple of 4, so the drain's 4 validity cmps collapse to one.
// u = 0.5*bn - dot via C init = 0.5*bn + negated-x B operand; d2 = 2u + xn.
__global__ __launch_bounds__(256, 5) void k_main(const float* __restrict__ x,
                                                 const _Float16* __restrict__ B16,
                                                 const float* __restrict__ bnorm,
                                                 float* __restrict__ cand) {
  __shared__ __align__(16) _Float16 Bs[CHUNK * 64];        // 16384 B, swizzled
  __shared__ float bns[CHUNK];                             //   512 B (0.5*bn)
  __shared__ float qmem[4][QSLOT * 64];                    // 13312 B -> 30208 B

  const int tid = threadIdx.x;
  const int w = tid >> 6, lane = tid & 63;
  const int quad = lane >> 4, l15 = lane & 15;
  const int row = blockIdx.y * ROWS_PER_BLOCK + w * 16 + l15;  // this lane's x-row
  const int pbase = blockIdx.x * PART_COLS;
  float* qf = &qmem[w][lane];                   // slot-major: qf[slot*64]

  // swizzled fragment-read bases (per-thread constants): lane reads col
  // mt*16+l15, logical blocks quad (k=quad*8..+7) and quad+4 (k=32+quad*8..).
  // physical = logical ^ (col&7) = logical ^ (l15&7)  [mt*16 == 0 mod 8]
  const int swA = quad ^ (l15 & 7);
  const int swB = swA ^ 4;
  const uint4* fragA = (const uint4*)Bs + l15 * 8 + swA;   // + mt*128 blocks via imm
  const uint4* fragB = (const uint4*)Bs + l15 * 8 + swB;

  // x fragments, NEGATED (B-operand: -x[k = quad*8+j + 32ks][n = l15]) + exact
  // fp32 norm xn (from the un-negated values).
  v8h nx0, nx1;
  float xn;
  {
    const float* xr = x + (size_t)row * DIM;
    const float4* xp0 = (const float4*)(xr + quad * 8);
    float4 a0 = xp0[0], a1 = xp0[1];
    const float4* xp1 = (const float4*)(xr + 32 + quad * 8);
    float4 c0 = xp1[0], c1 = xp1[1];
    v8h h0, h1;
    h0[0]=(_Float16)(-a0.x); h0[1]=(_Float16)(-a0.y); h0[2]=(_Float16)(-a0.z); h0[3]=(_Float16)(-a0.w);
    h0[4]=(_Float16)(-a1.x); h0[5]=(_Float16)(-a1.y); h0[6]=(_Float16)(-a1.z); h0[7]=(_Float16)(-a1.w);
    h1[0]=(_Float16)(-c0.x); h1[1]=(_Float16)(-c0.y); h1[2]=(_Float16)(-c0.z); h1[3]=(_Float16)(-c0.w);
    h1[4]=(_Float16)(-c1.x); h1[5]=(_Float16)(-c1.y); h1[6]=(_Float16)(-c1.z); h1[7]=(_Float16)(-c1.w);
    nx0 = h0; nx1 = h1;
    float s = a0.x*a0.x + a0.y*a0.y + a0.z*a0.z + a0.w*a0.w
            + a1.x*a1.x + a1.y*a1.y + a1.z*a1.z + a1.w*a1.w
            + c0.x*c0.x + c0.y*c0.y + c0.z*c0.z + c0.w*c0.w
            + c1.x*c1.x + c1.y*c1.y + c1.z*c1.z + c1.w*c1.w;
    s += __shfl_xor(s, 16);   // each quad holds a disjoint 16 of the 64 k's
    s += __shfl_xor(s, 32);
    xn = s;
  }

  float lst[KSEL];   // sorted ascending, u-space; lst[10] = private threshold
#pragma unroll
  for (int i = 0; i < KSEL; ++i) lst[i] = __builtin_inff();
  float thrx = __builtin_inff();   // u-space threshold: pass <=> u < thrx
  int qo = 0;                      // queue write cursor (slots, multiple of 4)

  // drain the queue (one 4-slot group per iteration) + tighten the threshold.
  // qo is a multiple of 4 and <= 12, so groups are all-valid or all-invalid:
  // one validity cmp masks all 4 values (invalid lanes insert inf = no-op).
  auto drain = [&]() {
    for (int i = 0; __ballot(i < qo); i += 4) {
      const float* qi = qf + i * 64;   // 4 reads: imm offsets 0/256/512/768
      float v0 = qi[0], v1 = qi[64], v2 = qi[128], v3 = qi[192];
      bool valid = i < qo;
      v0 = valid ? v0 : __builtin_inff();
      v1 = valid ? v1 : __builtin_inff();
      v2 = valid ? v2 : __builtin_inff();
      v3 = valid ? v3 : __builtin_inff();
      float m = fminf(fminf(v0, v1), fminf(v2, v3));
      if (__ballot(m < lst[KSEL - 1])) {   // any lane improves its list?
        bins11(v0, lst); bins11(v1, lst);  // v >= lst[10] inserts are no-ops
        bins11(v2, lst); bins11(v3, lst);
      }
    }
    qo = 0;
    float th = fminf(lst[KSEL - 1], __shfl_xor(lst[KSEL - 1], 16));
    th = fminf(th, __shfl_xor(th, 32));
    thrx = th;
  };

  // staging-prefetch in FOUR NAMED uint4 registers (no union, no array --
  // union-uint4 LDS stores are the R5/R14 scratch trigger). 2 threads/col,
  // each holds logical blocks shf*4 .. shf*4+3.
  const int scol = tid >> 1, shf = tid & 1;
  const int ssw = scol & 7;
  uint4* const stBase = (uint4*)Bs + scol * 8;
  uint4* const sd0 = stBase + ((shf * 4 + 0) ^ ssw);   // hoisted swizzled dsts
  uint4* const sd1 = stBase + ((shf * 4 + 1) ^ ssw);
  uint4* const sd2 = stBase + ((shf * 4 + 2) ^ ssw);
  uint4* const sd3 = stBase + ((shf * 4 + 3) ^ ssw);
  uint4 st0, st1, st2, st3;
  float pbn;
  {
    const uint4* src = (const uint4*)(B16 + (size_t)(pbase + scol) * DIM + shf * 32);
    st0 = src[0]; st1 = src[1]; st2 = src[2]; st3 = src[3];
    pbn = bnorm[pbase + (tid & (CHUNK - 1))];
  }

  for (int c = 0; c < NCHUNK; ++c) {
    const int cb = pbase + c * CHUNK;
    __syncthreads();   // Bs free (all waves done with previous chunk's reads)
    {
      sd0[0] = st0; sd1[0] = st1; sd2[0] = st2; sd3[0] = st3;  // 4x ds_write_b128
      if (tid < CHUNK) bns[tid] = pbn;
    }
    __syncthreads();   // staged

    // issue next chunk's loads now; latency hides behind scan+drain below
    if (c + 1 < NCHUNK) {
      const int nb = cb + CHUNK;
      const uint4* src = (const uint4*)(B16 + (size_t)(nb + scol) * DIM + shf * 32);
      st0 = src[0]; st1 = src[1]; st2 = src[2]; st3 = src[3];
      pbn = bnorm[nb + (tid & (CHUNK - 1))];
    }

    if (c == 0) {
      // warm-up: threshold is +inf -- insert u = acc directly (fp32-exact),
      // then establish the threshold.
#pragma unroll
      for (int mt = 0; mt < 8; ++mt) {
        v8h a0 = *(const v8h*)(fragA + mt * 128);   // ds_read_b128, imm mt*2048
        v8h a1 = *(const v8h*)(fragB + mt * 128);
        v4f acc = *(const v4f*)&bns[mt * 16 + quad * 4];   // C init = 0.5*bn
        acc = __builtin_amdgcn_mfma_f32_16x16x32_f16(a0, nx0, acc, 0, 0, 0);
        acc = __builtin_amdgcn_mfma_f32_16x16x32_f16(a1, nx1, acc, 0, 0, 0);
        bins11(acc[0], lst);               // acc == u, nothing else to compute
        bins11(acc[1], lst);
        bins11(acc[2], lst);
        bins11(acc[3], lst);
      }
      float th = fminf(lst[KSEL - 1], __shfl_xor(lst[KSEL - 1], 16));
      th = fminf(th, __shfl_xor(th, 32));
      thrx = th;
    } else {
#pragma unroll
      for (int mt = 0; mt < 8; ++mt) {
        // insurance: guarantee room for this mt's 4-slot group (qo <= 8
        // pre-push -> max write slot 11 < 13); rarely fires post-warm-up
        if (__ballot(qo > QCAP - 4)) drain();
        v8h a0 = *(const v8h*)(fragA + mt * 128);
        v8h a1 = *(const v8h*)(fragB + mt * 128);
        v4f acc = *(const v4f*)&bns[mt * 16 + quad * 4];   // C init = 0.5*bn
        acc = __builtin_amdgcn_mfma_f32_16x16x32_f16(a0, nx0, acc, 0, 0, 0);
        acc = __builtin_amdgcn_mfma_f32_16x16x32_f16(a1, nx1, acc, 0, 0, 0);
        // GROUP PUSH: always write the 4 slots; advance by 4 only if the
        // group min passes. Drop condition per candidate identical to the
        // per-candidate scheme (m >= thrx ==> every t >= thrx).
        float t0 = acc[0], t1 = acc[1], t2 = acc[2], t3 = acc[3];
        float m = fminf(fminf(t0, t1), fminf(t2, t3));
        float* qdst = qf + qo * 64;
        qdst[0]   = t0;
        qdst[64]  = t1;
        qdst[128] = t2;
        qdst[192] = t3;
        qo += (m < thrx) ? 4 : 0;
      }
      // end-of-chunk drain only at odd c (half the forced drains); insurance
      // bounds qo in between; c = NCHUNK-1 = 15 is odd -> queue empties
      // before the final merge.
      if ((c & 1) && __ballot(qo > 0)) drain();
    }
  }

  // merge the 4 quads' sorted lists (disjoint col subsets of the same row;
  // same xn per row, so u-space order == d2-space order)
#pragma unroll
  for (int s = 16; s <= 32; s <<= 1) {
    float other[KSEL];
#pragma unroll
    for (int j = 0; j < KSEL; ++j) other[j] = __shfl_xor(lst[j], s);
#pragma unroll
    for (int j = 0; j < KSEL; ++j) bins11(other[j], lst);
  }

  if (quad == 0) {   // one writer per row: cand layout [row][part][k], sorted
    float* dst = cand + (size_t)row * (PPART * KSEL) + blockIdx.x * KSEL;
#pragma unroll
    for (int i = 0; i < KSEL; ++i) dst[i] = fmaf(lst[i], 2.0f, xn);  // d2 = 2u+xn
  }
}

// ---------------- merge: wave per row, 704 = 64 lanes x 11 ----------------
__global__ __launch_bounds__(256) void k_merge(const float* __restrict__ cand,
                                               float* __restrict__ out) {
  int w = threadIdx.x >> 6, lane = threadIdx.x & 63;
  int row = blockIdx.x * 4 + w;
  const float* src = cand + (size_t)row * (PPART * KSEL) + lane * KSEL;
  float lst[KSEL];
#pragma unroll
  for (int i = 0; i < KSEL; ++i) lst[i] = src[i];
#pragma unroll
  for (int s = 1; s <= 32; s <<= 1) {
    float other[KSEL];
#pragma unroll
    for (int j = 0; j < KSEL; ++j) other[j] = __shfl_xor(lst[j], s);
#pragma unroll
    for (int j = 0; j < KSEL; ++j) bins11(other[j], lst);
  }
  if (lane == 0) {
    // lst sorted ascending: lst[0] is the self-match -> dropped
    float s = 0.0f;
#pragma unroll
    for (int j = 1; j < KSEL; ++j) s += sqrtf(fmaxf(lst[j], 0.0f));
    out[row] = log1pf(s * 0.1f);      // mean over k=10, log1p
  }
}

extern "C" void kernel_launch(void* const* d_in, const int* in_sizes, int n_in,
                              void* d_out, int out_size, void* d_ws, size_t ws_size,
                              hipStream_t stream) {
  (void)in_sizes; (void)n_in; (void)out_size; (void)ws_size;
  const float* x   = (const float*)d_in[0];   // 2048 x 64
  const float* buf = (const float*)d_in[1];   // 131072 x 64
  float* out = (float*)d_out;

  char* ws = (char*)d_ws;
  _Float16* B16 = (_Float16*)ws;                       // 16,777,216 B
  float* bnorm  = (float*)(ws + 16777216);             //    524,288 B
  float* cand   = (float*)(ws + 17301504);             //  5,767,168 B

  k_prep_b<<<dim3(2048), dim3(256), 0, stream>>>(buf, B16, bnorm);
  k_main<<<dim3(PPART, NR / ROWS_PER_BLOCK), dim3(256), 0, stream>>>(x, B16, bnorm, cand);
  k_merge<<<dim3(NR / 4), dim3(256), 0, stream>>>(cand, out);
}

// Round 17
// 212.338 us; speedup vs baseline: 1.3630x; 1.3630x over previous
//
#include <hip/hip_runtime.h>
#include <math.h>

// Problem constants (fixed by reference)
#define NR 2048
#define MC 131072
#define DIM 64
#define KSEL 11                    // k+1 smallest kept per row
#define PPART 64                   // column partitions
#define PART_COLS (MC / PPART)     // 2048 cols per partition
#define CHUNK 128                  // cols per LDS chunk
#define NCHUNK (PART_COLS / CHUNK) // 16
#define ROWS_PER_BLOCK 64          // 4 waves x 16 rows
#define QSLOT 13                   // f32 queue slots per lane, SLOT-MAJOR:
                                   // qmem[w][slot*64 + lane] -> bank = lane%32,
                                   // uniform 2 lanes/bank for ANY qo divergence
#define QCAP 12                    // usable slots (insurance keeps qo <= 12,
                                   // max write slot 11, max drain read slot 11)

typedef _Float16 v8h __attribute__((ext_vector_type(8)));
typedef float v4f __attribute__((ext_vector_type(4)));

// ---------------- prep: HALF-norm 0.5*|b|^2 (fp32) + buf -> f16 ----------------
// u-space: k_main computes u = 0.5*bn - dot = 0.5*(d2 - xn) directly in the
// MFMA accumulator (C init = 0.5*bn, x fragments negated).
__global__ __launch_bounds__(256) void k_prep_b(const float* __restrict__ buf,
                                                _Float16* __restrict__ B16,
                                                float* __restrict__ bnorm) {
  int gid = blockIdx.x * 256 + threadIdx.x;   // 4 threads per buffer row
  int row = gid >> 2, q = gid & 3;
  const float4* src = (const float4*)(buf + (size_t)row * DIM + q * 16);
  float4 f0 = src[0], f1 = src[1], f2 = src[2], f3 = src[3];
  float s = f0.x*f0.x + f0.y*f0.y + f0.z*f0.z + f0.w*f0.w
          + f1.x*f1.x + f1.y*f1.y + f1.z*f1.z + f1.w*f1.w
          + f2.x*f2.x + f2.y*f2.y + f2.z*f2.z + f2.w*f2.w
          + f3.x*f3.x + f3.y*f3.y + f3.z*f3.z + f3.w*f3.w;
  s += __shfl_xor(s, 1);
  s += __shfl_xor(s, 2);
  if (q == 0) bnorm[row] = s * 0.5f;          // HALF norm (u-space C operand)
  union { _Float16 h[16]; uint4 u[2]; } o;
  o.h[0]=(_Float16)f0.x; o.h[1]=(_Float16)f0.y; o.h[2]=(_Float16)f0.z; o.h[3]=(_Float16)f0.w;
  o.h[4]=(_Float16)f1.x; o.h[5]=(_Float16)f1.y; o.h[6]=(_Float16)f1.z; o.h[7]=(_Float16)f1.w;
  o.h[8]=(_Float16)f2.x; o.h[9]=(_Float16)f2.y; o.h[10]=(_Float16)f2.z; o.h[11]=(_Float16)f2.w;
  o.h[12]=(_Float16)f3.x; o.h[13]=(_Float16)f3.y; o.h[14]=(_Float16)f3.z; o.h[15]=(_Float16)f3.w;
  uint4* dst = (uint4*)(B16 + (size_t)row * DIM + q * 16);
  dst[0] = o.u[0]; dst[1] = o.u[1];
}

// branchless bubble-insert into sorted-ascending 11-list. Inserting any value
// >= lst[10] (incl. +inf) is a no-op (it bubbles off the end). 22 min/max ops.
__device__ __forceinline__ void bins11(float v, float lst[KSEL]) {
  float t = v;
#pragma unroll
  for (int j = 0; j < KSEL; ++j) {
    float a = fminf(lst[j], t);
    t = fmaxf(lst[j], t);
    lst[j] = a;
  }
}

// ---------------- main: MFMA in u-space + f32 queue + sorted top-11 ----------
// R15 EXACT REVERT (212.97us session best). R16's group-of-4 push regressed
// (queue volume = 4x true passes -> 4x drain iterations; lesson confirmed
// twice with R1: never let junk into the queue -- drain cost scales with
// slots, not passes). Structure: swizzled 16B-block tile (2x ds_read_b128/mt
// frags, conflict-free), named-register staging (union-uint4 LDS stores are
// the R5/R14 scratch trigger), slot-major f32 queue (bank = lane%32 for any
// qo divergence), per-candidate branchless pushes, odd-c drain cadence,
// 5 blocks/CU. u = 0.5*bn - dot via C init = 0.5*bn + negated-x B operand;
// d2 = 2u + xn recovered once at write-out.
__global__ __launch_bounds__(256, 5) void k_main(const float* __restrict__ x,
                                                 const _Float16* __restrict__ B16,
                                                 const float* __restrict__ bnorm,
                                                 float* __restrict__ cand) {
  __shared__ __align__(16) _Float16 Bs[CHUNK * 64];        // 16384 B, swizzled
  __shared__ float bns[CHUNK];                             //   512 B (0.5*bn)
  __shared__ float qmem[4][QSLOT * 64];                    // 13312 B -> 30208 B

  const int tid = threadIdx.x;
  const int w = tid >> 6, lane = tid & 63;
  const int quad = lane >> 4, l15 = lane & 15;
  const int row = blockIdx.y * ROWS_PER_BLOCK + w * 16 + l15;  // this lane's x-row
  const int pbase = blockIdx.x * PART_COLS;
  float* qf = &qmem[w][lane];                   // slot-major: qf[slot*64]

  // swizzled fragment-read bases (per-thread constants): lane reads col
  // mt*16+l15, logical blocks quad (k=quad*8..+7) and quad+4 (k=32+quad*8..).
  // physical = logical ^ (col&7) = logical ^ (l15&7)  [mt*16 == 0 mod 8]
  const int swA = quad ^ (l15 & 7);
  const int swB = swA ^ 4;
  const uint4* fragA = (const uint4*)Bs + l15 * 8 + swA;   // + mt*128 blocks via imm
  const uint4* fragB = (const uint4*)Bs + l15 * 8 + swB;

  // x fragments, NEGATED (B-operand: -x[k = quad*8+j + 32ks][n = l15]) + exact
  // fp32 norm xn (from the un-negated values).
  v8h nx0, nx1;
  float xn;
  {
    const float* xr = x + (size_t)row * DIM;
    const float4* xp0 = (const float4*)(xr + quad * 8);
    float4 a0 = xp0[0], a1 = xp0[1];
    const float4* xp1 = (const float4*)(xr + 32 + quad * 8);
    float4 c0 = xp1[0], c1 = xp1[1];
    v8h h0, h1;
    h0[0]=(_Float16)(-a0.x); h0[1]=(_Float16)(-a0.y); h0[2]=(_Float16)(-a0.z); h0[3]=(_Float16)(-a0.w);
    h0[4]=(_Float16)(-a1.x); h0[5]=(_Float16)(-a1.y); h0[6]=(_Float16)(-a1.z); h0[7]=(_Float16)(-a1.w);
    h1[0]=(_Float16)(-c0.x); h1[1]=(_Float16)(-c0.y); h1[2]=(_Float16)(-c0.z); h1[3]=(_Float16)(-c0.w);
    h1[4]=(_Float16)(-c1.x); h1[5]=(_Float16)(-c1.y); h1[6]=(_Float16)(-c1.z); h1[7]=(_Float16)(-c1.w);
    nx0 = h0; nx1 = h1;
    float s = a0.x*a0.x + a0.y*a0.y + a0.z*a0.z + a0.w*a0.w
            + a1.x*a1.x + a1.y*a1.y + a1.z*a1.z + a1.w*a1.w
            + c0.x*c0.x + c0.y*c0.y + c0.z*c0.z + c0.w*c0.w
            + c1.x*c1.x + c1.y*c1.y + c1.z*c1.z + c1.w*c1.w;
    s += __shfl_xor(s, 16);   // each quad holds a disjoint 16 of the 64 k's
    s += __shfl_xor(s, 32);
    xn = s;
  }

  float lst[KSEL];   // sorted ascending, u-space; lst[10] = private threshold
#pragma unroll
  for (int i = 0; i < KSEL; ++i) lst[i] = __builtin_inff();
  float thrx = __builtin_inff();   // u-space threshold: pass <=> u < thrx
  int qo = 0;                      // queue write cursor (slots)

  // drain the queue (4 slots per iteration) + tighten the shared threshold.
  // qo <= 12 always (insurance), so i <= 8 and reads reach at most slot 11.
  auto drain = [&]() {
    for (int i = 0; __ballot(i < qo); i += 4) {
      const float* qi = qf + i * 64;   // 4 reads: imm offsets 0/256/512/768
      float v0 = qi[0], v1 = qi[64], v2 = qi[128], v3 = qi[192];
      v0 = (i + 0 < qo) ? v0 : __builtin_inff();
      v1 = (i + 1 < qo) ? v1 : __builtin_inff();
      v2 = (i + 2 < qo) ? v2 : __builtin_inff();
      v3 = (i + 3 < qo) ? v3 : __builtin_inff();
      float m = fminf(fminf(v0, v1), fminf(v2, v3));
      if (__ballot(m < lst[KSEL - 1])) {   // any lane improves its list?
        bins11(v0, lst); bins11(v1, lst);  // v >= lst[10] inserts are no-ops
        bins11(v2, lst); bins11(v3, lst);
      }
    }
    qo = 0;
    float th = fminf(lst[KSEL - 1], __shfl_xor(lst[KSEL - 1], 16));
    th = fminf(th, __shfl_xor(th, 32));
    thrx = th;
  };

  // staging-prefetch in FOUR NAMED uint4 registers (no union, no array --
  // union-uint4 LDS stores are the R5/R14 scratch trigger). 2 threads/col,
  // each holds logical blocks shf*4 .. shf*4+3.
  const int scol = tid >> 1, shf = tid & 1;
  const int ssw = scol & 7;
  uint4* const stBase = (uint4*)Bs + scol * 8;
  uint4* const sd0 = stBase + ((shf * 4 + 0) ^ ssw);   // hoisted swizzled dsts
  uint4* const sd1 = stBase + ((shf * 4 + 1) ^ ssw);
  uint4* const sd2 = stBase + ((shf * 4 + 2) ^ ssw);
  uint4* const sd3 = stBase + ((shf * 4 + 3) ^ ssw);
  uint4 st0, st1, st2, st3;
  float pbn;
  {
    const uint4* src = (const uint4*)(B16 + (size_t)(pbase + scol) * DIM + shf * 32);
    st0 = src[0]; st1 = src[1]; st2 = src[2]; st3 = src[3];
    pbn = bnorm[pbase + (tid & (CHUNK - 1))];
  }

  for (int c = 0; c < NCHUNK; ++c) {
    const int cb = pbase + c * CHUNK;
    __syncthreads();   // Bs free (all waves done with previous chunk's reads)
    {
      sd0[0] = st0; sd1[0] = st1; sd2[0] = st2; sd3[0] = st3;  // 4x ds_write_b128
      if (tid < CHUNK) bns[tid] = pbn;
    }
    __syncthreads();   // staged

    // issue next chunk's loads now; latency hides behind scan+drain below
    if (c + 1 < NCHUNK) {
      const int nb = cb + CHUNK;
      const uint4* src = (const uint4*)(B16 + (size_t)(nb + scol) * DIM + shf * 32);
      st0 = src[0]; st1 = src[1]; st2 = src[2]; st3 = src[3];
      pbn = bnorm[nb + (tid & (CHUNK - 1))];
    }

    if (c == 0) {
      // warm-up: threshold is +inf -- insert u = acc directly (fp32-exact),
      // then establish the threshold.
#pragma unroll
      for (int mt = 0; mt < 8; ++mt) {
        v8h a0 = *(const v8h*)(fragA + mt * 128);   // ds_read_b128, imm mt*2048
        v8h a1 = *(const v8h*)(fragB + mt * 128);
        v4f acc = *(const v4f*)&bns[mt * 16 + quad * 4];   // C init = 0.5*bn
        acc = __builtin_amdgcn_mfma_f32_16x16x32_f16(a0, nx0, acc, 0, 0, 0);
        acc = __builtin_amdgcn_mfma_f32_16x16x32_f16(a1, nx1, acc, 0, 0, 0);
        bins11(acc[0], lst);               // acc == u, nothing else to compute
        bins11(acc[1], lst);
        bins11(acc[2], lst);
        bins11(acc[3], lst);
      }
      float th = fminf(lst[KSEL - 1], __shfl_xor(lst[KSEL - 1], 16));
      th = fminf(th, __shfl_xor(th, 32));
      thrx = th;
    } else {
#pragma unroll
      for (int mt = 0; mt < 8; ++mt) {
        // insurance: guarantee room for this mt's <=4 pushes (keeps qo <= 12;
        // post-warm-up the wave-max cursor stays low, this rarely fires)
        if (__ballot(qo > QCAP - 4)) drain();
        v8h a0 = *(const v8h*)(fragA + mt * 128);
        v8h a1 = *(const v8h*)(fragB + mt * 128);
        v4f acc = *(const v4f*)&bns[mt * 16 + quad * 4];   // C init = 0.5*bn
        acc = __builtin_amdgcn_mfma_f32_16x16x32_f16(a0, nx0, acc, 0, 0, 0);
        acc = __builtin_amdgcn_mfma_f32_16x16x32_f16(a1, nx1, acc, 0, 0, 0);
        // acc[j] == u_j: branchless slot-major pushes; always write, advance
        // on pass. Bank = lane%32 regardless of qo -> conflict-free.
        float t0 = acc[0], t1 = acc[1], t2 = acc[2], t3 = acc[3];
        qf[qo * 64] = t0; qo += (t0 < thrx) ? 1 : 0;
        qf[qo * 64] = t1; qo += (t1 < thrx) ? 1 : 0;
        qf[qo * 64] = t2; qo += (t2 < thrx) ? 1 : 0;
        qf[qo * 64] = t3; qo += (t3 < thrx) ? 1 : 0;
      }
      // end-of-chunk drain only at odd c (half the forced drains); insurance
      // bounds qo in between; c = NCHUNK-1 = 15 is odd -> queue empties
      // before the final merge.
      if ((c & 1) && __ballot(qo > 0)) drain();
    }
  }

  // merge the 4 quads' sorted lists (disjoint col subsets of the same row;
  // same xn per row, so u-space order == d2-space order)
#pragma unroll
  for (int s = 16; s <= 32; s <<= 1) {
    float other[KSEL];
#pragma unroll
    for (int j = 0; j < KSEL; ++j) other[j] = __shfl_xor(lst[j], s);
#pragma unroll
    for (int j = 0; j < KSEL; ++j) bins11(other[j], lst);
  }

  if (quad == 0) {   // one writer per row: cand layout [row][part][k], sorted
    float* dst = cand + (size_t)row * (PPART * KSEL) + blockIdx.x * KSEL;
#pragma unroll
    for (int i = 0; i < KSEL; ++i) dst[i] = fmaf(lst[i], 2.0f, xn);  // d2 = 2u+xn
  }
}

// ---------------- merge: wave per row, 704 = 64 lanes x 11 ----------------
__global__ __launch_bounds__(256) void k_merge(const float* __restrict__ cand,
                                               float* __restrict__ out) {
  int w = threadIdx.x >> 6, lane = threadIdx.x & 63;
  int row = blockIdx.x * 4 + w;
  const float* src = cand + (size_t)row * (PPART * KSEL) + lane * KSEL;
  float lst[KSEL];
#pragma unroll
  for (int i = 0; i < KSEL; ++i) lst[i] = src[i];
#pragma unroll
  for (int s = 1; s <= 32; s <<= 1) {
    float other[KSEL];
#pragma unroll
    for (int j = 0; j < KSEL; ++j) other[j] = __shfl_xor(lst[j], s);
#pragma unroll
    for (int j = 0; j < KSEL; ++j) bins11(other[j], lst);
  }
  if (lane == 0) {
    // lst sorted ascending: lst[0] is the self-match -> dropped
    float s = 0.0f;
#pragma unroll
    for (int j = 1; j < KSEL; ++j) s += sqrtf(fmaxf(lst[j], 0.0f));
    out[row] = log1pf(s * 0.1f);      // mean over k=10, log1p
  }
}

extern "C" void kernel_launch(void* const* d_in, const int* in_sizes, int n_in,
                              void* d_out, int out_size, void* d_ws, size_t ws_size,
                              hipStream_t stream) {
  (void)in_sizes; (void)n_in; (void)out_size; (void)ws_size;
  const float* x   = (const float*)d_in[0];   // 2048 x 64
  const float* buf = (const float*)d_in[1];   // 131072 x 64
  float* out = (float*)d_out;

  char* ws = (char*)d_ws;
  _Float16* B16 = (_Float16*)ws;                       // 16,777,216 B
  float* bnorm  = (float*)(ws + 16777216);             //    524,288 B
  float* cand   = (float*)(ws + 17301504);             //  5,767,168 B

  k_prep_b<<<dim3(2048), dim3(256), 0, stream>>>(buf, B16, bnorm);
  k_main<<<dim3(PPART, NR / ROWS_PER_BLOCK), dim3(256), 0, stream>>>(x, B16, bnorm, cand);
  k_merge<<<dim3(NR / 4), dim3(256), 0, stream>>>(cand, out);
}